// Round 4
// baseline (888.419 us; speedup 1.0000x reference)
//
#include <hip/hip_runtime.h>

__device__ __forceinline__ float sigf(float x){ return 1.0f/(1.0f+__expf(-x)); }

#define Bn 16
#define Tn 128
#define Fn 40
#define Hn 64
#define Dn 80   // 2F
#define NHn 5
#define DKn 16
#define FFn 320

// ---------------- Stage A: per-feature LSTMs (q,k,v) ----------------
// grid (640, 3), block 256. n = bi*40+f. xf[n,t] = x[bi,t,f].
__global__ __launch_bounds__(256) void k_feat_lstm(
    const float* __restrict__ x,
    const float* __restrict__ qWih, const float* __restrict__ qWhh, const float* __restrict__ qb,
    const float* __restrict__ kWih, const float* __restrict__ kWhh, const float* __restrict__ kb,
    const float* __restrict__ vWih, const float* __restrict__ vWhh, const float* __restrict__ vb,
    float* __restrict__ hq, float* __restrict__ hk, float* __restrict__ hv)
{
  const int n = blockIdx.x;
  const int which = blockIdx.y;
  const int bi = n / Fn, f = n % Fn;
  const float* xrowp = x + (bi*Tn)*Fn + f;   // stride Fn per t
  if (which == 2) {
    if (threadIdx.x == 0) {
      float wih[4], whh[4], bbv[4];
      #pragma unroll
      for (int g=0; g<4; ++g){ wih[g]=vWih[g]; whh[g]=vWhh[g]; bbv[g]=vb[g]; }
      float h=0.f, c=0.f;
      for (int t=0;t<Tn;++t){
        float xt = xrowp[t*Fn];
        float zi = xt*wih[0]+h*whh[0]+bbv[0];
        float zf = xt*wih[1]+h*whh[1]+bbv[1];
        float zg = xt*wih[2]+h*whh[2]+bbv[2];
        float zo = xt*wih[3]+h*whh[3]+bbv[3];
        c = sigf(zf)*c + sigf(zi)*tanhf(zg);
        h = sigf(zo)*tanhf(c);
      }
      hv[n] = h;
    }
    return;
  }
  const float* Wih = which ? kWih : qWih;
  const float* Whh = which ? kWhh : qWhh;
  const float* bia = which ? kb  : qb;
  float* outp = which ? hk : hq;

  __shared__ float hbuf[Hn];
  __shared__ float zbuf[4*Hn];
  const int g = threadIdx.x;
  const float wih = Wih[g];
  const float bb  = bia[g];
  float whh[Hn];
  #pragma unroll
  for (int j=0;j<Hn;++j) whh[j] = Whh[g*Hn+j];
  if (g < Hn) hbuf[g] = 0.f;
  float c = 0.f;
  __syncthreads();
  for (int t=0;t<Tn;++t){
    float xt = xrowp[t*Fn];
    float a0=0.f,a1=0.f,a2=0.f,a3=0.f;
    #pragma unroll
    for (int j=0;j<Hn;j+=4){
      a0 += hbuf[j  ]*whh[j  ];
      a1 += hbuf[j+1]*whh[j+1];
      a2 += hbuf[j+2]*whh[j+2];
      a3 += hbuf[j+3]*whh[j+3];
    }
    zbuf[g] = xt*wih + bb + ((a0+a1)+(a2+a3));
    __syncthreads();
    if (g < Hn){
      float zi=zbuf[g], zf=zbuf[g+Hn], zg=zbuf[g+2*Hn], zo=zbuf[g+3*Hn];
      c = sigf(zf)*c + sigf(zi)*tanhf(zg);
      hbuf[g] = sigf(zo)*tanhf(c);
    }
    __syncthreads();
  }
  if (g < Hn) outp[n*Hn + g] = hbuf[g];
}

// ---------------- Stage B1: feature attention softmax (writes output b) ----------------
// grid 640 (= bi*40+i), block 64
__global__ __launch_bounds__(64) void k_featattn(
    const float* __restrict__ hq, const float* __restrict__ hk, const float* __restrict__ hv,
    float* __restrict__ Wsm, float* __restrict__ out_b)
{
  const int blk = blockIdx.x;
  const int bi = blk / Fn, i = blk % Fn;
  const int j = threadIdx.x;
  __shared__ float qrow[Hn];
  qrow[j] = hq[blk*Hn + j];
  __syncthreads();
  float s = -1e30f;
  if (j < Fn){
    const float* krow = hk + (bi*Fn + j)*Hn;
    float a = 0.f;
    #pragma unroll
    for (int h2=0; h2<Hn; ++h2) a += qrow[h2]*krow[h2];
    s = a * 0.125f * hv[bi*Fn + j];   // /sqrt(64) * V
  }
  float m = s;
  #pragma unroll
  for (int off=32; off>0; off>>=1) m = fmaxf(m, __shfl_xor(m, off));
  float e = (j < Fn) ? __expf(s - m) : 0.f;
  float tot = e;
  #pragma unroll
  for (int off=32; off>0; off>>=1) tot += __shfl_xor(tot, off);
  float p = e / tot;
  if (j < Fn){
    Wsm[blk*Fn + j] = p;
    out_b[bi*(Fn*Fn) + j*Fn + i] = p;   // b = Wsm.transpose(0,2,1)
  }
}

// ---------------- Stage B2: attn_output + src concat ----------------
// grid 2048 (= bi*128+t), block 128
__global__ __launch_bounds__(128) void k_build_src(
    const float* __restrict__ x, const float* __restrict__ Wsm, float* __restrict__ src)
{
  const int blk = blockIdx.x;
  const int bi = blk / Tn;
  const int tid = threadIdx.x;
  __shared__ float xrow[Fn];
  if (tid < Fn) xrow[tid] = x[blk*Fn + tid];
  __syncthreads();
  if (tid < Fn){
    src[blk*Dn + tid] = xrow[tid];
  } else if (tid < Dn){
    const int i = tid - Fn;
    const float* wrow = Wsm + (bi*Fn + i)*Fn;
    float a = 0.f;
    #pragma unroll
    for (int j2=0;j2<Fn;++j2) a += xrow[j2]*wrow[j2];
    src[blk*Dn + tid] = a;
  }
}

// ---------------- Transformer: qkv projection (group shuffle; k,v from q!) ----------------
// grid 2048, block 128
__global__ __launch_bounds__(128) void k_qkv(
    const float* __restrict__ src,
    const float* __restrict__ Wq, const float* __restrict__ bq,
    const float* __restrict__ Wk, const float* __restrict__ bk,
    const float* __restrict__ Wv, const float* __restrict__ bv,
    float* __restrict__ q, float* __restrict__ k, float* __restrict__ v)
{
  const int row = blockIdx.x;
  const int t = threadIdx.x;
  __shared__ float qs[Dn];
  __shared__ float qrow[Dn];
  if (t < Dn) qs[t] = src[row*Dn + (t%5)*16 + t/5];   // channel shuffle
  __syncthreads();
  if (t < Dn){
    const float* wr = Wq + t*Dn;
    float a = bq[t];
    #pragma unroll 8
    for (int d2=0; d2<Dn; ++d2) a += qs[d2]*wr[d2];
    qrow[t] = a;
    q[row*Dn + t] = a;
  }
  __syncthreads();
  if (t < Dn){
    const float* wk = Wk + t*Dn;
    const float* wv = Wv + t*Dn;
    float ak = bk[t], av = bv[t];
    #pragma unroll 8
    for (int d2=0; d2<Dn; ++d2){ float qq = qrow[d2]; ak += qq*wk[d2]; av += qq*wv[d2]; }
    k[row*Dn + t] = ak;
    v[row*Dn + t] = av;
  }
}

// ---------------- Transformer: attention per (s1,h,bi); writes output c ----------------
// grid (128, 5, 16), block 128
__global__ __launch_bounds__(128) void k_attn(
    const float* __restrict__ q, const float* __restrict__ k, const float* __restrict__ v,
    float* __restrict__ o, float* __restrict__ c_out)
{
  const int s1 = blockIdx.x, h = blockIdx.y, bi = blockIdx.z;
  const int s2 = threadIdx.x;
  __shared__ float qf[DKn];
  __shared__ float p[Tn];
  __shared__ float red_m[2];
  __shared__ float red_s[2];
  if (s2 < DKn) qf[s2] = q[(bi*Tn + s1)*Dn + h*DKn + s2];
  __syncthreads();
  const float* krow = k + (bi*Tn + s2)*Dn + h*DKn;
  float a = 0.f;
  #pragma unroll
  for (int d2=0; d2<DKn; ++d2) a += qf[d2]*krow[d2];
  a *= 0.25f;  // 1/sqrt(16)
  const int wv_id = s2 >> 6;
  float m = a;
  #pragma unroll
  for (int off=32; off>0; off>>=1) m = fmaxf(m, __shfl_xor(m, off));
  if ((s2 & 63) == 0) red_m[wv_id] = m;
  __syncthreads();
  m = fmaxf(red_m[0], red_m[1]);
  float e = __expf(a - m);
  float tot = e;
  #pragma unroll
  for (int off=32; off>0; off>>=1) tot += __shfl_xor(tot, off);
  if ((s2 & 63) == 0) red_s[wv_id] = tot;
  __syncthreads();
  tot = red_s[0] + red_s[1];
  float pv = e / tot;
  p[s2] = pv;
  c_out[((bi*NHn + h)*Tn + s1)*Tn + s2] = pv;
  __syncthreads();
  if (s2 < DKn){
    const float* vcol = v + bi*Tn*Dn + h*DKn + s2;
    float acc = 0.f;
    for (int j2=0;j2<Tn;++j2) acc += p[j2]*vcol[j2*Dn];
    o[(bi*Tn + s1)*Dn + h*DKn + s2] = acc;
  }
}

// ---------------- Transformer: Wo + residual + LayerNorm ----------------
// grid 2048, block 128
__global__ __launch_bounds__(128) void k_o_ln(
    const float* __restrict__ o, const float* __restrict__ Wo, const float* __restrict__ bo,
    const float* __restrict__ lng, const float* __restrict__ lnb, float* __restrict__ src)
{
  const int row = blockIdx.x;
  const int t = threadIdx.x;
  __shared__ float orow[Dn];
  __shared__ float red[128];
  if (t < Dn) orow[t] = o[row*Dn + t];
  __syncthreads();
  float val = 0.f;
  if (t < Dn){
    const float* wr = Wo + t*Dn;
    float a = bo[t];
    #pragma unroll 8
    for (int d2=0; d2<Dn; ++d2) a += orow[d2]*wr[d2];
    val = a + src[row*Dn + t];
  }
  red[t] = (t < Dn) ? val : 0.f;
  __syncthreads();
  for (int s=64; s>0; s>>=1){ if (t < s) red[t] += red[t+s]; __syncthreads(); }
  const float mean = red[0] * (1.f/Dn);
  __syncthreads();
  float dv = (t < Dn) ? (val - mean) : 0.f;
  red[t] = dv*dv;
  __syncthreads();
  for (int s=64; s>0; s>>=1){ if (t < s) red[t] += red[t+s]; __syncthreads(); }
  const float rstd = rsqrtf(red[0]*(1.f/Dn) + 1e-5f);
  if (t < Dn) src[row*Dn + t] = (val - mean)*rstd*lng[t] + lnb[t];
}

// ---------------- Transformer: FF + residual + LayerNorm ----------------
// grid 2048, block 320
__global__ __launch_bounds__(320) void k_ff_ln(
    const float* __restrict__ W1, const float* __restrict__ b1,
    const float* __restrict__ W2, const float* __restrict__ b2,
    const float* __restrict__ lng, const float* __restrict__ lnb, float* __restrict__ src)
{
  const int row = blockIdx.x;
  const int t = threadIdx.x;
  __shared__ float srow[Dn];
  __shared__ float h1[FFn];
  __shared__ float red[128];
  if (t < Dn) srow[t] = src[row*Dn + t];
  __syncthreads();
  {
    const float* wr = W1 + t*Dn;
    float a = b1[t];
    #pragma unroll 8
    for (int d2=0; d2<Dn; ++d2) a += srow[d2]*wr[d2];
    h1[t] = fmaxf(a, 0.f);
  }
  __syncthreads();
  float val = 0.f;
  if (t < Dn){
    const float* wr = W2 + t*FFn;
    float a = b2[t];
    #pragma unroll 8
    for (int d2=0; d2<FFn; ++d2) a += h1[d2]*wr[d2];
    val = a + srow[t];
  }
  if (t < 128) red[t] = (t < Dn) ? val : 0.f;
  __syncthreads();
  for (int s=64; s>0; s>>=1){ if (t < s) red[t] += red[t+s]; __syncthreads(); }
  const float mean = red[0] * (1.f/Dn);
  __syncthreads();
  if (t < 128){ float dv = (t < Dn) ? (val - mean) : 0.f; red[t] = dv*dv; }
  __syncthreads();
  for (int s=64; s>0; s>>=1){ if (t < s) red[t] += red[t+s]; __syncthreads(); }
  const float rstd = rsqrtf(red[0]*(1.f/Dn) + 1e-5f);
  if (t < Dn) src[row*Dn + t] = (val - mean)*rstd*lng[t] + lnb[t];
}

// ---------------- BiLSTM: parallel input projection gx = X @ Wih.T + b ----------------
// grid (2048, 2), block 256
__global__ __launch_bounds__(256) void k_gx(
    const float* __restrict__ X, int inD,
    const float* __restrict__ WihF, const float* __restrict__ bF,
    const float* __restrict__ WihB, const float* __restrict__ bB,
    float* __restrict__ gx)
{
  const int row = blockIdx.x;      // n*128 + t
  const int dir = blockIdx.y;
  const int g = threadIdx.x;
  __shared__ float xs[128];
  for (int d2=g; d2<inD; d2+=256) xs[d2] = X[row*inD + d2];
  __syncthreads();
  const float* W  = dir ? WihB : WihF;
  const float* bb = dir ? bB  : bF;
  const float* wr = W + g*inD;
  float a = bb[g];
  for (int d2=0; d2<inD; ++d2) a += xs[d2]*wr[d2];
  gx[dir*(Bn*Tn*256) + row*256 + g] = a;
}

// ---------------- BiLSTM: sequential recurrence ----------------
// grid (16, 2), block 256. out[n,t, dir*64 + h]
__global__ __launch_bounds__(256) void k_bilstm_rec(
    const float* __restrict__ gx,
    const float* __restrict__ WhhF, const float* __restrict__ WhhB,
    float* __restrict__ outp)
{
  const int n = blockIdx.x;
  const int dir = blockIdx.y;
  const int g = threadIdx.x;
  const float* Whh = dir ? WhhB : WhhF;
  float whh[Hn];
  #pragma unroll
  for (int j=0;j<Hn;++j) whh[j] = Whh[g*Hn+j];
  __shared__ float hbuf[Hn];
  __shared__ float zbuf[4*Hn];
  if (g < Hn) hbuf[g] = 0.f;
  float c = 0.f;
  __syncthreads();
  const float* gxd = gx + dir*(Bn*Tn*256);
  for (int step=0; step<Tn; ++step){
    const int t = dir ? (Tn-1-step) : step;
    float a0=0.f,a1=0.f,a2=0.f,a3=0.f;
    #pragma unroll
    for (int j=0;j<Hn;j+=4){
      a0 += hbuf[j  ]*whh[j  ];
      a1 += hbuf[j+1]*whh[j+1];
      a2 += hbuf[j+2]*whh[j+2];
      a3 += hbuf[j+3]*whh[j+3];
    }
    zbuf[g] = gxd[(n*Tn + t)*256 + g] + ((a0+a1)+(a2+a3));
    __syncthreads();
    if (g < Hn){
      float zi=zbuf[g], zf=zbuf[g+Hn], zg=zbuf[g+2*Hn], zo=zbuf[g+3*Hn];
      c = sigf(zf)*c + sigf(zi)*tanhf(zg);
      hbuf[g] = sigf(zo)*tanhf(c);
    }
    __syncthreads();
    if (g < Hn) outp[(n*Tn + t)*128 + dir*Hn + g] = hbuf[g];
  }
}

// ---------------- Final: relu(last step) -> fc1 -> relu -> fc2 ----------------
// grid 16, block 128
__global__ __launch_bounds__(128) void k_final(
    const float* __restrict__ out1,
    const float* __restrict__ fc1W, const float* __restrict__ fc1b,
    const float* __restrict__ fc2W, const float* __restrict__ fc2b,
    float* __restrict__ outp)
{
  const int n = blockIdx.x;
  const int t = threadIdx.x;
  __shared__ float r[128];
  __shared__ float a1[64];
  r[t] = fmaxf(out1[(n*Tn + (Tn-1))*128 + t], 0.f);
  __syncthreads();
  if (t < 64){
    const float* wr = fc1W + t*128;
    float a = fc1b[t];
    #pragma unroll 8
    for (int d2=0; d2<128; ++d2) a += r[d2]*wr[d2];
    a1[t] = fmaxf(a, 0.f);
  }
  __syncthreads();
  if (t == 0){
    float a = fc2b[0];
    #pragma unroll 8
    for (int d2=0; d2<64; ++d2) a += a1[d2]*fc2W[d2];
    outp[n] = a;
  }
}

extern "C" void kernel_launch(void* const* d_in, const int* in_sizes, int n_in,
                              void* d_out, int out_size, void* d_ws, size_t ws_size,
                              hipStream_t stream)
{
  const float* x     = (const float*)d_in[0];
  const float* qWih  = (const float*)d_in[1];
  const float* qWhh  = (const float*)d_in[2];
  const float* qb    = (const float*)d_in[3];
  const float* kWih  = (const float*)d_in[4];
  const float* kWhh  = (const float*)d_in[5];
  const float* kb    = (const float*)d_in[6];
  const float* vWih  = (const float*)d_in[7];
  const float* vWhh  = (const float*)d_in[8];
  const float* vb    = (const float*)d_in[9];
  const float* tWq   = (const float*)d_in[10];
  const float* tbq   = (const float*)d_in[11];
  const float* tWk   = (const float*)d_in[12];
  const float* tbk   = (const float*)d_in[13];
  const float* tWv   = (const float*)d_in[14];
  const float* tbv   = (const float*)d_in[15];
  const float* tWo   = (const float*)d_in[16];
  const float* tbo   = (const float*)d_in[17];
  const float* tW1   = (const float*)d_in[18];
  const float* tb1   = (const float*)d_in[19];
  const float* tW2   = (const float*)d_in[20];
  const float* tb2   = (const float*)d_in[21];
  const float* tlng  = (const float*)d_in[22];
  const float* tlnb  = (const float*)d_in[23];
  const float* l0fWih= (const float*)d_in[24];
  const float* l0fWhh= (const float*)d_in[25];
  const float* l0fb  = (const float*)d_in[26];
  const float* l0bWih= (const float*)d_in[27];
  const float* l0bWhh= (const float*)d_in[28];
  const float* l0bb  = (const float*)d_in[29];
  const float* l1fWih= (const float*)d_in[30];
  const float* l1fWhh= (const float*)d_in[31];
  const float* l1fb  = (const float*)d_in[32];
  const float* l1bWih= (const float*)d_in[33];
  const float* l1bWhh= (const float*)d_in[34];
  const float* l1bb  = (const float*)d_in[35];
  const float* fc1W  = (const float*)d_in[36];
  const float* fc1b  = (const float*)d_in[37];
  const float* fc2W  = (const float*)d_in[38];
  const float* fc2b  = (const float*)d_in[39];

  // fp32 workspace, no aliasing, total 2,500,224 floats = 9.54 MB
  float* ws  = (float*)d_ws;
  float* hq  = ws;                      // 40960
  float* hk  = hq  + 640*64;            // 40960
  float* hv  = hk  + 640*64;            // 640
  float* Wsm = hv  + 640;               // 25600
  float* src = Wsm + 16*40*40;          // 163840
  float* q   = src + 16*128*80;
  float* k   = q   + 16*128*80;
  float* v   = k   + 16*128*80;
  float* o   = v   + 16*128*80;
  float* gx  = o   + 16*128*80;         // 2 * 16*128*256 = 1048576
  float* lout0 = gx + 2*16*128*256;     // 262144
  float* lout1 = lout0 + 16*128*128;    // 262144

  float* outp  = (float*)d_out;            // [16] (out [B,1])
  float* out_b = outp + 16;                // [16,40,40]
  float* out_c = out_b + 16*40*40;         // [2,16,5,128,128]

  // Stage A: per-feature LSTMs
  k_feat_lstm<<<dim3(640,3), 256, 0, stream>>>(x, qWih,qWhh,qb, kWih,kWhh,kb, vWih,vWhh,vb, hq,hk,hv);
  // Stage B
  k_featattn<<<640, 64, 0, stream>>>(hq, hk, hv, Wsm, out_b);
  k_build_src<<<2048, 128, 0, stream>>>(x, Wsm, src);
  // Transformer layers
  for (int l=0; l<2; ++l){
    k_qkv<<<2048, 128, 0, stream>>>(src, tWq + l*Dn*Dn, tbq + l*Dn,
                                    tWk + l*Dn*Dn, tbk + l*Dn,
                                    tWv + l*Dn*Dn, tbv + l*Dn, q, k, v);
    k_attn<<<dim3(128,5,16), 128, 0, stream>>>(q, k, v, o, out_c + (size_t)l*16*5*128*128);
    k_o_ln<<<2048, 128, 0, stream>>>(o, tWo + l*Dn*Dn, tbo + l*Dn, tlng + l*Dn, tlnb + l*Dn, src);
    k_ff_ln<<<2048, 320, 0, stream>>>(tW1 + l*FFn*Dn, tb1 + l*FFn, tW2 + l*Dn*FFn, tb2 + l*Dn,
                                      tlng + l*Dn, tlnb + l*Dn, src);
  }
  // BiLSTM layer 0 (inD=80)
  k_gx<<<dim3(2048,2), 256, 0, stream>>>(src, 80, l0fWih, l0fb, l0bWih, l0bb, gx);
  k_bilstm_rec<<<dim3(16,2), 256, 0, stream>>>(gx, l0fWhh, l0bWhh, lout0);
  // BiLSTM layer 1 (inD=128)
  k_gx<<<dim3(2048,2), 256, 0, stream>>>(lout0, 128, l1fWih, l1fb, l1bWih, l1bb, gx);
  k_bilstm_rec<<<dim3(16,2), 256, 0, stream>>>(gx, l1fWhh, l1bWhh, lout1);
  // Final head
  k_final<<<16, 128, 0, stream>>>(lout1, fc1W, fc1b, fc2W, fc2b, outp);
}